// Round 5
// baseline (29.454 us; speedup 1.0000x reference)
//
#include <hip/hip_runtime.h>

// Son_swapnet: out[b,i] = sum_j d*leaky01(t3)*(-w3[e(i,j)]),
//   d  = x[b,i]*w1[i] - x[b,j]*w1[j]
//   t3 = c0 + a*(c1 + a*(c2 + a*c3)), a = |d|
//   leaky01(t) = max(t, 0.01t)
// j==i contributes exactly 0 (wrow entry forced to 0).
//
// Layout: 512 thr = 8 waves, each wave owns 1 node i and 32 batches.
// Half-wave j-split: lanes 0-31 cover j in [0,128), lanes 32-63 j in [128,256);
// final __shfl_xor(acc,32) merges. LDS 40KB -> 4 blocks/CU -> 8 waves/SIMD.

#define C_NODES 256
#define BT      32      // batches per block
#define NW      8       // waves per block (512 threads), 1 node per wave

__global__ __launch_bounds__(512, 8) void son_kernel(
    const float* __restrict__ x, const float* __restrict__ w1,
    const float* __restrict__ w2, const float* __restrict__ w3,
    float* __restrict__ out)
{
    // o1t: [row=batch 0..31][channel], 256 words/row, 16B-chunk XOR-swizzled by (row&7)
    __shared__ __align__(16) float o1t[BT * C_NODES];       // 32 KiB
    __shared__ __align__(16) float wrow[NW * C_NODES];      // 8 KiB: [w][j] = -w3[e(i_w,j)]

    const int t  = threadIdx.x;
    const int b0 = blockIdx.x * BT;

    // ---- stage o1t (coalesced global float4 reads; swizzled LDS writes)
    {
        const int chunk = t & 63;            // 16B chunk within row
        const int c4    = chunk << 2;        // channel
        const float4 w1v = *(const float4*)&w1[c4];
        #pragma unroll
        for (int p = 0; p < 4; ++p) {
            const int row = (t >> 6) + (p << 3);          // 0..31
            const float4 xv = *(const float4*)&x[(b0 + row) * C_NODES + c4];
            float4 o;
            o.x = xv.x * w1v.x; o.y = xv.y * w1v.y;
            o.z = xv.z * w1v.z; o.w = xv.w * w1v.w;
            const int phys = chunk ^ (row & 7);
            *(float4*)&o1t[(row << 8) + (phys << 2)] = o;
        }
    }

    // ---- gather wrow[w][j] = -w3[e(i,j)]  (L2-resident scattered reads, once)
    {
        const int lane = t & 63;
        const int wv_  = t >> 6;             // wave = node slot
        const int i    = blockIdx.y * NW + wv_;
        float4 wv;
        #pragma unroll
        for (int k = 0; k < 4; ++k) {
            const int j = lane * 4 + k;
            const int p = (i < j) ? i : j;
            const int q = (i < j) ? j : i;
            ((float*)&wv)[k] = (i == j) ? 0.f
                             : -w3[(p * (511 - p)) / 2 + q - p - 1];
        }
        *(float4*)&wrow[(wv_ << 8) + (lane << 2)] = wv;
    }
    __syncthreads();

    const int lane    = t & 63;
    const int w       = __builtin_amdgcn_readfirstlane(t >> 6);
    const int i       = blockIdx.y * NW + w;
    const int row     = lane & 31;                 // batch within tile
    const int hbit    = lane & 32;                 // j-half selector (bit 5)
    const int swz     = row & 7;
    const int rowbase = row << 8;

    const float c0 = w2[0], c1 = w2[1], c2 = w2[2], c3 = w2[3];

    // own-node o1 value (swizzled one-time read)
    const float oi = o1t[rowbase + ((((i >> 2) ^ swz) << 2) | (i & 3))];

    float acc = 0.f;

    #pragma unroll 8
    for (int jc = 0; jc < 32; ++jc) {
        const int cj = hbit + jc;                              // chunk 0..63
        const float4 ov = *(const float4*)&o1t[rowbase + ((cj ^ swz) << 2)];
        const float4 wa = *(const float4*)&wrow[(w << 8) + (cj << 2)];  // 2 addrs/wave
        #pragma unroll
        for (int k = 0; k < 4; ++k) {
            const float oj  = ((const float*)&ov)[k];
            const float d   = oi - oj;
            const float a   = fabsf(d);                     // folds to abs-modifier
            const float t3  = __builtin_fmaf(a, __builtin_fmaf(a,
                                __builtin_fmaf(a, c3, c2), c1), c0);
            const float t3s = fmaxf(t3, 0.01f * t3);        // leaky on t3
            acc = __builtin_fmaf(d * t3s, ((const float*)&wa)[k], acc);
        }
    }

    // merge the two j-halves (lane l <-> l+32), then lanes 0-31 store
    acc += __shfl_xor(acc, 32, 64);
    if (lane < 32)
        out[(b0 + row) * C_NODES + i] = acc;
}

extern "C" void kernel_launch(void* const* d_in, const int* in_sizes, int n_in,
                              void* d_out, int out_size, void* d_ws, size_t ws_size,
                              hipStream_t stream) {
    const float* x  = (const float*)d_in[0];
    const float* w1 = (const float*)d_in[1];
    const float* w2 = (const float*)d_in[2];
    const float* w3 = (const float*)d_in[3];
    float* out = (float*)d_out;

    const int B = in_sizes[0] / C_NODES;          // 1024
    dim3 grid(B / BT, C_NODES / NW);              // 32 x 32 = 1024 blocks = 4/CU
    son_kernel<<<grid, 512, 0, stream>>>(x, w1, w2, w3, out);
}

// Round 6
// 26.473 us; speedup vs baseline: 1.1126x; 1.1126x over previous
//
#include <hip/hip_runtime.h>

// Son_swapnet: out[b,i] = sum_j d*leaky01(t3)*(-w3[e(i,j)]),
//   d  = x[b,i]*w1[i] - x[b,j]*w1[j]
//   t3 = c0 + a*(c1 + a*(c2 + a*c3)), a = |d|
//   leaky01(t) = max(t, 0.01t)
// j==i contributes exactly 0 (W[i][i] forced to 0).
//
// Two kernels:
//  1) build_W: W[i][j] = -w3[e(i,j)] into d_ws (256 KB, L2-resident).
//  2) son_kernel: wave = 1 node i (uniform -> W row via SCALAR loads),
//     lane = batch; o1 tile swizzled in LDS; 1 ds_read_b128 per 4 partners.

#define C_NODES 256
#define BT      64      // batches per block (one per lane)
#define NW      8       // waves per block (512 threads), 1 node per wave

__global__ __launch_bounds__(256) void build_W(const float* __restrict__ w3,
                                               float* __restrict__ W)
{
    const int i = blockIdx.x;
    const int j = threadIdx.x;
    const int p = (i < j) ? i : j;
    const int q = (i < j) ? j : i;
    W[(i << 8) + j] = (i == j) ? 0.f
                    : -w3[(p * (511 - p)) / 2 + q - p - 1];
}

__global__ __launch_bounds__(512, 4) void son_kernel(
    const float* __restrict__ x, const float* __restrict__ w1,
    const float* __restrict__ w2, const float* __restrict__ W,
    float* __restrict__ out)
{
    // o1t: [row=batch][channel], 256 words/row, 16B-chunk XOR-swizzled by (row&7)
    __shared__ __align__(16) float o1t[BT * C_NODES];       // 64 KiB

    const int t  = threadIdx.x;
    const int b0 = blockIdx.x * BT;

    // ---- stage o1t (coalesced global float4 reads; swizzled LDS writes)
    {
        const int chunk = t & 63;            // 16B chunk within row
        const int c4    = chunk << 2;        // channel
        const float4 w1v = *(const float4*)&w1[c4];
        #pragma unroll
        for (int p = 0; p < 8; ++p) {
            const int row = (t >> 6) + (p << 3);          // 0..63
            const float4 xv = *(const float4*)&x[(b0 + row) * C_NODES + c4];
            float4 o;
            o.x = xv.x * w1v.x; o.y = xv.y * w1v.y;
            o.z = xv.z * w1v.z; o.w = xv.w * w1v.w;
            const int phys = chunk ^ (row & 7);
            *(float4*)&o1t[(row << 8) + (phys << 2)] = o;
        }
    }
    __syncthreads();

    const int lane    = t & 63;
    const int w       = __builtin_amdgcn_readfirstlane(t >> 6);
    const int i       = blockIdx.y * NW + w;
    const int swz     = lane & 7;
    const int rowbase = lane << 8;

    const float c0 = w2[0], c1 = w2[1], c2 = w2[2], c3 = w2[3];
    const float* __restrict__ Wrow = W + (i << 8);   // uniform -> scalar loads

    // own-node o1 value (swizzled one-time read)
    const float oi = o1t[rowbase + ((((i >> 2) ^ swz) << 2) | (i & 3))];

    float acc0 = 0.f, acc1 = 0.f, acc2 = 0.f, acc3 = 0.f;

    #pragma unroll 8
    for (int jc = 0; jc < 64; ++jc) {
        const float4 ov = *(const float4*)&o1t[rowbase + ((jc ^ swz) << 2)]; // 4 partners
        const float w0 = Wrow[4 * jc + 0];   // wave-uniform -> s_load, SGPR operand
        const float w1s = Wrow[4 * jc + 1];
        const float w2s = Wrow[4 * jc + 2];
        const float w3s = Wrow[4 * jc + 3];

        {   const float d = oi - ov.x, a = fabsf(d);
            const float t3 = __builtin_fmaf(a, __builtin_fmaf(a,
                               __builtin_fmaf(a, c3, c2), c1), c0);
            acc0 = __builtin_fmaf(d * fmaxf(t3, 0.01f * t3), w0, acc0); }
        {   const float d = oi - ov.y, a = fabsf(d);
            const float t3 = __builtin_fmaf(a, __builtin_fmaf(a,
                               __builtin_fmaf(a, c3, c2), c1), c0);
            acc1 = __builtin_fmaf(d * fmaxf(t3, 0.01f * t3), w1s, acc1); }
        {   const float d = oi - ov.z, a = fabsf(d);
            const float t3 = __builtin_fmaf(a, __builtin_fmaf(a,
                               __builtin_fmaf(a, c3, c2), c1), c0);
            acc2 = __builtin_fmaf(d * fmaxf(t3, 0.01f * t3), w2s, acc2); }
        {   const float d = oi - ov.w, a = fabsf(d);
            const float t3 = __builtin_fmaf(a, __builtin_fmaf(a,
                               __builtin_fmaf(a, c3, c2), c1), c0);
            acc3 = __builtin_fmaf(d * fmaxf(t3, 0.01f * t3), w3s, acc3); }
    }

    out[(b0 + lane) * C_NODES + i] = (acc0 + acc1) + (acc2 + acc3);
}

extern "C" void kernel_launch(void* const* d_in, const int* in_sizes, int n_in,
                              void* d_out, int out_size, void* d_ws, size_t ws_size,
                              hipStream_t stream) {
    const float* x  = (const float*)d_in[0];
    const float* w1 = (const float*)d_in[1];
    const float* w2 = (const float*)d_in[2];
    const float* w3 = (const float*)d_in[3];
    float* out = (float*)d_out;
    float* W   = (float*)d_ws;                    // 256*256*4 = 256 KB scratch

    build_W<<<C_NODES, C_NODES, 0, stream>>>(w3, W);

    const int B = in_sizes[0] / C_NODES;          // 1024
    dim3 grid(B / BT, C_NODES / NW);              // 16 x 32 = 512 blocks = 2/CU
    son_kernel<<<grid, 512, 0, stream>>>(x, w1, w2, W, out);
}